// Round 17
// baseline (61.234 us; speedup 1.0000x reference)
//
#include <hip/hip_runtime.h>
#include <math.h>

// NeRF ray-march forward (MipRayMarcher2): PERSISTENT WAVES + SW-PIPELINED
// group prefetch. 2048 single-wave blocks; each wave processes 8 consecutive
// 16-ray groups with ping-pong register sets: while computing group k, group
// k+1's entire load set (dep/den 26 + colors 36 floats) is in flight, pinned
// live via asm so the compiler cannot sink the loads. Cold HBM latency is
// paid once per wave instead of once per group.
// Per group (as R16): march operands direct global->reg (13 consecutive
// dwords/lane); log2-optical-depth march; quad prefix-SUM splice; LDS only
// for the weight transpose-store and color chunk tiles. Zero barriers.
// nRays = 262144, 48 samples, 47 intervals.

#define S_SAMPLES 48
#define S_INTERVALS 47
#define WR 16       // rays per group
#define RSTRIDE 52  // LDS dwords per ray row
#define BT 64       // one wave per block
#define GPB 8       // groups per wave
#define WAVE_LDS (2 * WR * RSTRIDE)  // 1664 dwords = 6656 B

struct Grp {
    float4 dA, dB4, dC, nA, nB4, nC;
    float dD, nD;
    float4 u0, u1, u2, u3, u4, u5, u6, u7, u8;
};

struct LaneCtx {
    int lane, r, q, rbase, base, mbase, offD;
    int rc0, rc1, rc2;        // color float4 indices (chunk 0)
    int b0, b1, b2;           // LDS color-tile write offsets (dwords)
    float* A;
    float* B;
};

__device__ __forceinline__ void load_grp(Grp& S, const LaneCtx& L,
                                         const float* __restrict__ depths,
                                         const float* __restrict__ densities,
                                         const float* __restrict__ colors,
                                         int grp) {
    const float* gdepf = depths + (size_t)grp * (WR * S_SAMPLES);
    const float* gdenf = densities + (size_t)grp * (WR * S_SAMPLES);
    const float4* gcol4 = (const float4*)(colors + (size_t)grp * (WR * S_SAMPLES * 3));
    S.dA = *(const float4*)&gdepf[L.mbase];
    S.dB4 = *(const float4*)&gdepf[L.mbase + 4];
    S.dC = *(const float4*)&gdepf[L.mbase + 8];
    S.dD = gdepf[L.mbase + L.offD];
    S.nA = *(const float4*)&gdenf[L.mbase];
    S.nB4 = *(const float4*)&gdenf[L.mbase + 4];
    S.nC = *(const float4*)&gdenf[L.mbase + 8];
    S.nD = gdenf[L.mbase + L.offD];
    S.u0 = gcol4[L.rc0];
    S.u1 = gcol4[L.rc1];
    S.u2 = gcol4[L.rc2];
    S.u3 = gcol4[L.rc0 + 12];
    S.u4 = gcol4[L.rc1 + 12];
    S.u5 = gcol4[L.rc2 + 12];
    S.u6 = gcol4[L.rc0 + 24];
    S.u7 = gcol4[L.rc1 + 24];
    S.u8 = gcol4[L.rc2 + 24];
}

__device__ __forceinline__ void pin_grp(Grp& S) {
    asm volatile("" : "+v"(S.dA.x), "+v"(S.dA.y), "+v"(S.dA.z), "+v"(S.dA.w),
                      "+v"(S.dB4.x), "+v"(S.dB4.y), "+v"(S.dB4.z), "+v"(S.dB4.w),
                      "+v"(S.dC.x), "+v"(S.dC.y), "+v"(S.dC.z), "+v"(S.dC.w),
                      "+v"(S.dD), "+v"(S.nD));
    asm volatile("" : "+v"(S.nA.x), "+v"(S.nA.y), "+v"(S.nA.z), "+v"(S.nA.w),
                      "+v"(S.nB4.x), "+v"(S.nB4.y), "+v"(S.nB4.z), "+v"(S.nB4.w),
                      "+v"(S.nC.x), "+v"(S.nC.y), "+v"(S.nC.z), "+v"(S.nC.w));
    asm volatile("" : "+v"(S.u0.x), "+v"(S.u0.y), "+v"(S.u0.z), "+v"(S.u0.w),
                      "+v"(S.u1.x), "+v"(S.u1.y), "+v"(S.u1.z), "+v"(S.u1.w),
                      "+v"(S.u2.x), "+v"(S.u2.y), "+v"(S.u2.z), "+v"(S.u2.w),
                      "+v"(S.u3.x), "+v"(S.u3.y), "+v"(S.u3.z), "+v"(S.u3.w));
    asm volatile("" : "+v"(S.u4.x), "+v"(S.u4.y), "+v"(S.u4.z), "+v"(S.u4.w),
                      "+v"(S.u5.x), "+v"(S.u5.y), "+v"(S.u5.z), "+v"(S.u5.w),
                      "+v"(S.u6.x), "+v"(S.u6.y), "+v"(S.u6.z), "+v"(S.u6.w),
                      "+v"(S.u7.x), "+v"(S.u7.y), "+v"(S.u7.z), "+v"(S.u7.w));
    asm volatile("" : "+v"(S.u8.x), "+v"(S.u8.y), "+v"(S.u8.z), "+v"(S.u8.w));
}

__device__ __forceinline__ void compute_grp(
    Grp& S, const LaneCtx& L, int grp,
    float* __restrict__ out_rgb, float* __restrict__ out_depth,
    float* __restrict__ out_w) {
    const size_t wray = (size_t)grp * WR;
    const int lane = L.lane, q = L.q, r = L.r;
    const int rbase = L.rbase, base = L.base;
    float* A = L.A;
    float* B = L.B;
    const float LOG2E = 1.4426950408889634f;

    // ---- optical depths (log2 units) ----
    float g0, g1, g2, g3, g4, g5, g6, g7, g8, g9, g10, g11;
#define DD(dP, dN, nP, nN, OUT, HAS)                                   \
    do {                                                               \
        float xs = (0.5f * ((nP) + (nN)) - 1.f) * LOG2E;               \
        float sp2 = fmaxf(xs, 0.f) + log2f(1.f + exp2f(-fabsf(xs)));   \
        OUT = (HAS) ? ((dN) - (dP)) * sp2 : 0.f;                       \
    } while (0)
    DD(S.dA.x, S.dA.y, S.nA.x, S.nA.y, g0, true);
    DD(S.dA.y, S.dA.z, S.nA.y, S.nA.z, g1, true);
    DD(S.dA.z, S.dA.w, S.nA.z, S.nA.w, g2, true);
    DD(S.dA.w, S.dB4.x, S.nA.w, S.nB4.x, g3, true);
    DD(S.dB4.x, S.dB4.y, S.nB4.x, S.nB4.y, g4, true);
    DD(S.dB4.y, S.dB4.z, S.nB4.y, S.nB4.z, g5, true);
    DD(S.dB4.z, S.dB4.w, S.nB4.z, S.nB4.w, g6, true);
    DD(S.dB4.w, S.dC.x, S.nB4.w, S.nC.x, g7, true);
    DD(S.dC.x, S.dC.y, S.nC.x, S.nC.y, g8, true);
    DD(S.dC.y, S.dC.z, S.nC.y, S.nC.z, g9, true);
    DD(S.dC.z, S.dC.w, S.nC.z, S.nC.w, g10, true);
    DD(S.dC.w, S.dD, S.nC.w, S.nD, g11, (q < 3));
#undef DD

    float S1 = g0, S2 = S1 + g1, S3 = S2 + g2, S4 = S3 + g3;
    float S5 = S4 + g4, S6 = S5 + g5, S7 = S6 + g6, S8 = S7 + g7;
    float S9 = S8 + g8, S10 = S9 + g9, S11 = S10 + g10, S12 = S11 + g11;

    // ---- quad exclusive prefix SUM of total optical depth ----
    float Sloc = S12;
    float u1s = __shfl_up(Sloc, 1);
    float ps = (q >= 1) ? Sloc + u1s : Sloc;
    float u2s = __shfl_up(ps, 2);
    float incl = (q >= 2) ? ps + u2s : ps;
    float u3s = __shfl_up(incl, 1);
    float Sexc = (q >= 1) ? u3s : 0.f;

    float Tp = exp2f(-Sexc);
    float T1 = exp2f(-(Sexc + S1)), T2 = exp2f(-(Sexc + S2));
    float T3 = exp2f(-(Sexc + S3)), T4 = exp2f(-(Sexc + S4));
    float T5 = exp2f(-(Sexc + S5)), T6 = exp2f(-(Sexc + S6));
    float T7 = exp2f(-(Sexc + S7)), T8 = exp2f(-(Sexc + S8));
    float T9 = exp2f(-(Sexc + S9)), T10 = exp2f(-(Sexc + S10));
    float T11 = exp2f(-(Sexc + S11)), T12 = exp2f(-(Sexc + S12));
    float W0 = Tp - T1, W1 = T1 - T2, W2 = T2 - T3, W3 = T3 - T4;
    float W4 = T4 - T5, W5 = T5 - T6, W6 = T6 - T7, W7 = T7 - T8;
    float W8 = T8 - T9, W9 = T9 - T10, W10 = T10 - T11, W11 = T11 - T12;

    float ad = 0.f;
    ad = fmaf(W0, 0.5f * (S.dA.x + S.dA.y), ad);
    ad = fmaf(W1, 0.5f * (S.dA.y + S.dA.z), ad);
    ad = fmaf(W2, 0.5f * (S.dA.z + S.dA.w), ad);
    ad = fmaf(W3, 0.5f * (S.dA.w + S.dB4.x), ad);
    ad = fmaf(W4, 0.5f * (S.dB4.x + S.dB4.y), ad);
    ad = fmaf(W5, 0.5f * (S.dB4.y + S.dB4.z), ad);
    ad = fmaf(W6, 0.5f * (S.dB4.z + S.dB4.w), ad);
    ad = fmaf(W7, 0.5f * (S.dB4.w + S.dC.x), ad);
    ad = fmaf(W8, 0.5f * (S.dC.x + S.dC.y), ad);
    ad = fmaf(W9, 0.5f * (S.dC.y + S.dC.z), ad);
    ad = fmaf(W10, 0.5f * (S.dC.z + S.dC.w), ad);
    ad = fmaf(W11, 0.5f * (S.dC.w + S.dD), ad);
    float aw = Tp - T12;

    // ===== weights -> A, b128 =====
    *(float4*)&A[base + 0] = make_float4(W0, W1, W2, W3);
    *(float4*)&A[base + 4] = make_float4(W4, W5, W6, W7);
    *(float4*)&A[base + 8] = make_float4(W8, W9, W10, W11);

#pragma unroll
    for (int off = 1; off <= 2; off <<= 1) {
        aw += __shfl_xor(aw, off);
        ad += __shfl_xor(ad, off);
    }
    float lastDep = __shfl(S.dC.w, lane | 3);
    float firstDep = __shfl(S.dA.x, lane & ~3);
    if (q == 0) {
        float d = ad / aw;
        d = fminf(fmaxf(d, firstDep), lastDep);
        out_depth[wray + r] = d;
    }

    // ===== v values, all in regs =====
    float Wm1 = __shfl_up(W11, 1);
    if (q == 0) Wm1 = 0.f;
    float v0 = 0.5f * (Wm1 + W0), v1 = 0.5f * (W0 + W1);
    float v2 = 0.5f * (W1 + W2), v3 = 0.5f * (W2 + W3);
    float v4 = 0.5f * (W3 + W4), v5 = 0.5f * (W4 + W5);
    float v6 = 0.5f * (W5 + W6), v7 = 0.5f * (W6 + W7);
    float v8 = 0.5f * (W7 + W8), v9 = 0.5f * (W8 + W9);
    float v10 = 0.5f * (W9 + W10), v11 = 0.5f * (W10 + W11);

    asm volatile("" ::: "memory");  // wei writes precede store reads

    // ===== weight store: LDS(A) -> dense coalesced global =====
    {
        float* gw = out_w + wray * S_INTERVALS;
#pragma unroll
        for (int k = 0; k < 12; ++k) {
            int g = lane + k * 64;
            if (g < WR * S_INTERVALS) {
                int ray = g / S_INTERVALS;
                int s = g - ray * S_INTERVALS;
                gw[g] = A[ray * RSTRIDE + s];
            }
        }
    }

    // ===== color phase: 3 register-resident chunks through B =====
    float a0 = 0.f, a1 = 0.f, a2 = 0.f;
#define ACC4(vA, vB, vC, vD, fa, fb, fc)                                \
    do {                                                                \
        a0 = fmaf(vA, (fa).x, a0); a1 = fmaf(vA, (fa).y, a1);           \
        a2 = fmaf(vA, (fa).z, a2); a0 = fmaf(vB, (fa).w, a0);           \
        a1 = fmaf(vB, (fb).x, a1); a2 = fmaf(vB, (fb).y, a2);           \
        a0 = fmaf(vC, (fb).z, a0); a1 = fmaf(vC, (fb).w, a1);           \
        a2 = fmaf(vC, (fc).x, a2); a0 = fmaf(vD, (fc).y, a0);           \
        a1 = fmaf(vD, (fc).z, a1); a2 = fmaf(vD, (fc).w, a2);           \
    } while (0)
#define LD3(f, loc)                                                     \
    float4 f##a = *(const float4*)&B[rbase + (loc)];                    \
    float4 f##b = *(const float4*)&B[rbase + (loc) + 4];                \
    float4 f##c = *(const float4*)&B[rbase + (loc) + 8];
#define STAGE(pa, pb, pc)                                               \
    do {                                                                \
        *(float4*)&B[L.b0] = pa;                                        \
        *(float4*)&B[L.b1] = pb;                                        \
        *(float4*)&B[L.b2] = pc;                                        \
    } while (0)

    asm volatile("" ::: "memory");  // prior tile reads precede overwrite
    STAGE(S.u0, S.u1, S.u2);
    asm volatile("" ::: "memory");
    if (q == 0) {
        LD3(x, 0) LD3(y, 12) LD3(z, 24)
        ACC4(v0, v1, v2, v3, xa, xb, xc);
        ACC4(v4, v5, v6, v7, ya, yb, yc);
        ACC4(v8, v9, v10, v11, za, zb, zc);
    } else if (q == 1) {
        LD3(x, 36)
        ACC4(v0, v1, v2, v3, xa, xb, xc);
    }
    asm volatile("" ::: "memory");
    STAGE(S.u3, S.u4, S.u5);
    asm volatile("" ::: "memory");
    if (q == 1) {
        LD3(x, 0) LD3(y, 12)
        ACC4(v4, v5, v6, v7, xa, xb, xc);
        ACC4(v8, v9, v10, v11, ya, yb, yc);
    } else if (q == 2) {
        LD3(x, 24) LD3(y, 36)
        ACC4(v0, v1, v2, v3, xa, xb, xc);
        ACC4(v4, v5, v6, v7, ya, yb, yc);
    }
    asm volatile("" ::: "memory");
    STAGE(S.u6, S.u7, S.u8);
    asm volatile("" ::: "memory");
    if (q == 2) {
        LD3(x, 0)
        ACC4(v8, v9, v10, v11, xa, xb, xc);
    } else if (q == 3) {
        LD3(x, 12) LD3(y, 24) LD3(z, 36)
        ACC4(v0, v1, v2, v3, xa, xb, xc);
        ACC4(v4, v5, v6, v7, ya, yb, yc);
        ACC4(v8, v9, v10, v11, za, zb, zc);
    }
#undef STAGE
#undef LD3
#undef ACC4

#pragma unroll
    for (int off = 1; off <= 2; off <<= 1) {
        a0 += __shfl_xor(a0, off);
        a1 += __shfl_xor(a1, off);
        a2 += __shfl_xor(a2, off);
    }
    if (q == 0) {
        size_t rb = (wray + r) * 3;
        out_rgb[rb + 0] = fmaf(a0, 2.f, -1.f);
        out_rgb[rb + 1] = fmaf(a1, 2.f, -1.f);
        out_rgb[rb + 2] = fmaf(a2, 2.f, -1.f);
    }
}

__global__ __launch_bounds__(BT, 2) void raymarch_kernel(
    const float* __restrict__ colors,
    const float* __restrict__ densities,
    const float* __restrict__ depths,
    float* __restrict__ out_rgb,
    float* __restrict__ out_depth,
    float* __restrict__ out_w,
    int nRays) {
    __shared__ float4 smem4[WAVE_LDS / 4];
    LaneCtx L;
    L.lane = threadIdx.x;
    L.r = L.lane >> 2;
    L.q = L.lane & 3;
    L.rbase = L.r * RSTRIDE;
    L.base = L.rbase + 12 * L.q;
    L.mbase = 12 * L.lane;
    L.offD = (L.q < 3) ? 12 : 11;
    {
        int rr0 = L.lane / 12, i40 = L.lane - rr0 * 12;
        int f1 = L.lane + 64, rr1 = f1 / 12, i41 = f1 - rr1 * 12;
        int f2 = L.lane + 128, rr2 = f2 / 12, i42 = f2 - rr2 * 12;
        L.rc0 = rr0 * 36 + i40;
        L.rc1 = rr1 * 36 + i41;
        L.rc2 = rr2 * 36 + i42;
        L.b0 = rr0 * RSTRIDE + i40 * 4;
        L.b1 = rr1 * RSTRIDE + i41 * 4;
        L.b2 = rr2 * RSTRIDE + i42 * 4;
    }
    L.A = (float*)smem4;
    L.B = L.A + WR * RSTRIDE;

    const int gbase = blockIdx.x * GPB;

    Grp sA, sB;
    load_grp(sA, L, depths, densities, colors, gbase);

#pragma unroll
    for (int ii = 0; ii < GPB / 2; ++ii) {
        // phase 1: compute even group, prefetch odd
        load_grp(sB, L, depths, densities, colors, gbase + 2 * ii + 1);
        compute_grp(sA, L, gbase + 2 * ii, out_rgb, out_depth, out_w);
        pin_grp(sB);
        // phase 2: compute odd group, prefetch next even
        if (ii < GPB / 2 - 1)
            load_grp(sA, L, depths, densities, colors, gbase + 2 * ii + 2);
        compute_grp(sB, L, gbase + 2 * ii + 1, out_rgb, out_depth, out_w);
        if (ii < GPB / 2 - 1) pin_grp(sA);
    }
}

extern "C" void kernel_launch(void* const* d_in, const int* in_sizes, int n_in,
                              void* d_out, int out_size, void* d_ws, size_t ws_size,
                              hipStream_t stream) {
    const float* colors = (const float*)d_in[0];
    const float* densities = (const float*)d_in[1];
    const float* depths = (const float*)d_in[2];

    const int nRays = in_sizes[2] / S_SAMPLES;  // 262144
    const int nGroups = nRays / WR;             // 16384
    const int nBlocks = nGroups / GPB;          // 2048

    float* out = (float*)d_out;
    float* out_rgb = out;                        // nRays*3
    float* out_depth = out + (size_t)nRays * 3;  // nRays
    float* out_w = out + (size_t)nRays * 4;      // nRays*47

    raymarch_kernel<<<nBlocks, BT, 0, stream>>>(
        colors, densities, depths, out_rgb, out_depth, out_w, nRays);
}

// Round 18
// 51.911 us; speedup vs baseline: 1.1796x; 1.1796x over previous
//
#include <hip/hip_runtime.h>
#include <math.h>

// NeRF ray-march forward (MipRayMarcher2), SINGLE-KERNEL, log-space march,
// ALL-UPFRONT LOADS. 64-lane wave owns 16 rays (4 threads/ray). LDS per wave:
// two [16][52] row-major-per-ray buffers (16B-aligned rows):
//   A: depths (staging) -> weights (after march)
//   B: densities (staging) -> color chunk tile (x3, after march)
// All global loads (dep, den, 9x color float4) issue in one burst at kernel
// start; color regs are pinned live across the march via asm "+v" so the
// compiler cannot sink the loads into the color phase (mid-kernel stalls).
// March in log2 optical depth: quad splice is a prefix SUM; T = exp2(-cumsum);
// w_j = T_{j-1} - T_j arrives globally scaled. Reference's global depth clamp
// is the identity on real outputs (convex combo of the ray's mid depths);
// per-ray clamp covers the degenerate path for free. Zero barriers.
// BEST MEASURED: 52.07 us ~ 93% of the 6.29 TB/s memory-system ceiling
// (305 MB mandatory traffic). nRays = 262144, 48 samples, 47 intervals.

#define S_SAMPLES 48
#define S_INTERVALS 47
#define WR 16       // rays per wave
#define RSTRIDE 52  // dwords per ray row (48 + 4 pad; keeps 16B alignment)
#define WAVES 2
#define BT (WAVES * 64)
#define WAVE_LDS (2 * WR * RSTRIDE)  // 1664 dwords = 6656 B

__global__ __launch_bounds__(BT, 4) void raymarch_kernel(
    const float* __restrict__ colors,     // [nRays, 48, 3]
    const float* __restrict__ densities,  // [nRays, 48]
    const float* __restrict__ depths,     // [nRays, 48]
    float* __restrict__ out_rgb,          // [nRays, 3]
    float* __restrict__ out_depth,        // [nRays]
    float* __restrict__ out_w,            // [nRays, 47]
    int nRays) {
    __shared__ float4 smem4[WAVES * WAVE_LDS / 4];
    const int wid = threadIdx.x >> 6;
    const int lane = threadIdx.x & 63;
    float* A = (float*)smem4 + wid * WAVE_LDS;  // dep -> wei
    float* B = A + WR * RSTRIDE;                // den -> color tile

    const int waveId = blockIdx.x * WAVES + wid;
    const size_t wray = (size_t)waveId * WR;

    // ===== one VMEM burst: dep/den staging + ALL 9 color float4 =====
    const float4* gdep = (const float4*)(depths + wray * S_SAMPLES);
    const float4* gden = (const float4*)(densities + wray * S_SAMPLES);
    const float4* gcol4 = (const float4*)(colors + wray * (S_SAMPLES * 3));
    const int rr0 = lane / 12, i40 = lane - rr0 * 12;
    const int f1 = lane + 64, rr1 = f1 / 12, i41 = f1 - rr1 * 12;
    const int f2 = lane + 128, rr2 = f2 / 12, i42 = f2 - rr2 * 12;

    float4 u0 = gcol4[rr0 * 36 + i40];       // chunk 0
    float4 u1 = gcol4[rr1 * 36 + i41];
    float4 u2 = gcol4[rr2 * 36 + i42];
    float4 u3 = gcol4[rr0 * 36 + 12 + i40];  // chunk 1
    float4 u4 = gcol4[rr1 * 36 + 12 + i41];
    float4 u5 = gcol4[rr2 * 36 + 12 + i42];
    float4 u6 = gcol4[rr0 * 36 + 24 + i40];  // chunk 2
    float4 u7 = gcol4[rr1 * 36 + 24 + i41];
    float4 u8 = gcol4[rr2 * 36 + 24 + i42];

    {
#pragma unroll
        for (int k = 0; k < 3; ++k) {
            int fidx = lane + k * 64;  // 0..191 (12 float4 per ray)
            int rr = fidx / 12;
            int i4 = fidx - rr * 12;
            *(float4*)&A[rr * RSTRIDE + i4 * 4] = gdep[fidx];
            *(float4*)&B[rr * RSTRIDE + i4 * 4] = gden[fidx];
        }
        if (lane < WR) {  // zero row pads (q==3 reads A/B[rbase+48])
            float4 z = make_float4(0.f, 0.f, 0.f, 0.f);
            *(float4*)&A[lane * RSTRIDE + 48] = z;
            *(float4*)&B[lane * RSTRIDE + 48] = z;
        }
    }

    const int r = lane >> 2;  // local ray 0..15
    const int q = lane & 3;   // quad slot: intervals 12q..12q+11
    const int rbase = r * RSTRIDE;
    const int base = rbase + 12 * q;

    asm volatile("" ::: "memory");  // staging writes precede march reads

    // ===== march reads: 13 consecutive dwords per buffer, b128 =====
    const float4 dA = *(const float4*)&A[base + 0];
    const float4 dB4 = *(const float4*)&A[base + 4];
    const float4 dC = *(const float4*)&A[base + 8];
    const float dD = A[base + 12];  // q==3: zeroed pad (masked anyway)
    const float4 nA = *(const float4*)&B[base + 0];
    const float4 nB4 = *(const float4*)&B[base + 4];
    const float4 nC = *(const float4*)&B[base + 8];
    const float nD = B[base + 12];

    const float LOG2E = 1.4426950408889634f;

    // ---- optical depths (log2 units), independent per interval ----
    float g0, g1, g2, g3, g4, g5, g6, g7, g8, g9, g10, g11;
#define DD(dP, dN, nP, nN, OUT, HAS)                                   \
    do {                                                               \
        float xs = (0.5f * ((nP) + (nN)) - 1.f) * LOG2E;               \
        float sp2 = fmaxf(xs, 0.f) + log2f(1.f + exp2f(-fabsf(xs)));   \
        OUT = (HAS) ? ((dN) - (dP)) * sp2 : 0.f;                       \
    } while (0)
    DD(dA.x, dA.y, nA.x, nA.y, g0, true);
    DD(dA.y, dA.z, nA.y, nA.z, g1, true);
    DD(dA.z, dA.w, nA.z, nA.w, g2, true);
    DD(dA.w, dB4.x, nA.w, nB4.x, g3, true);
    DD(dB4.x, dB4.y, nB4.x, nB4.y, g4, true);
    DD(dB4.y, dB4.z, nB4.y, nB4.z, g5, true);
    DD(dB4.z, dB4.w, nB4.z, nB4.w, g6, true);
    DD(dB4.w, dC.x, nB4.w, nC.x, g7, true);
    DD(dC.x, dC.y, nC.x, nC.y, g8, true);
    DD(dC.y, dC.z, nC.y, nC.z, g9, true);
    DD(dC.z, dC.w, nC.z, nC.w, g10, true);
    DD(dC.w, dD, nC.w, nD, g11, (q < 3));
#undef DD

    // ---- local cumulative optical depth (pure add chain) ----
    float S1 = g0, S2 = S1 + g1, S3 = S2 + g2, S4 = S3 + g3;
    float S5 = S4 + g4, S6 = S5 + g5, S7 = S6 + g6, S8 = S7 + g7;
    float S9 = S8 + g8, S10 = S9 + g9, S11 = S10 + g10, S12 = S11 + g11;

    // ---- quad exclusive prefix SUM of total optical depth ----
    float Sloc = S12;
    float u1s = __shfl_up(Sloc, 1);
    float ps = (q >= 1) ? Sloc + u1s : Sloc;
    float u2s = __shfl_up(ps, 2);
    float incl = (q >= 2) ? ps + u2s : ps;
    float u3s = __shfl_up(incl, 1);
    float Sexc = (q >= 1) ? u3s : 0.f;

    // ---- transmittances (independent exp2) and global weights ----
    float Tp = exp2f(-Sexc);
    float T1 = exp2f(-(Sexc + S1)), T2 = exp2f(-(Sexc + S2));
    float T3 = exp2f(-(Sexc + S3)), T4 = exp2f(-(Sexc + S4));
    float T5 = exp2f(-(Sexc + S5)), T6 = exp2f(-(Sexc + S6));
    float T7 = exp2f(-(Sexc + S7)), T8 = exp2f(-(Sexc + S8));
    float T9 = exp2f(-(Sexc + S9)), T10 = exp2f(-(Sexc + S10));
    float T11 = exp2f(-(Sexc + S11)), T12 = exp2f(-(Sexc + S12));
    float W0 = Tp - T1, W1 = T1 - T2, W2 = T2 - T3, W3 = T3 - T4;
    float W4 = T4 - T5, W5 = T5 - T6, W6 = T6 - T7, W7 = T7 - T8;
    float W8 = T8 - T9, W9 = T9 - T10, W10 = T10 - T11, W11 = T11 - T12;

    // ---- weighted depth sum (weights already global) ----
    float ad = 0.f;
    ad = fmaf(W0, 0.5f * (dA.x + dA.y), ad);
    ad = fmaf(W1, 0.5f * (dA.y + dA.z), ad);
    ad = fmaf(W2, 0.5f * (dA.z + dA.w), ad);
    ad = fmaf(W3, 0.5f * (dA.w + dB4.x), ad);
    ad = fmaf(W4, 0.5f * (dB4.x + dB4.y), ad);
    ad = fmaf(W5, 0.5f * (dB4.y + dB4.z), ad);
    ad = fmaf(W6, 0.5f * (dB4.z + dB4.w), ad);
    ad = fmaf(W7, 0.5f * (dB4.w + dC.x), ad);
    ad = fmaf(W8, 0.5f * (dC.x + dC.y), ad);
    ad = fmaf(W9, 0.5f * (dC.y + dC.z), ad);
    ad = fmaf(W10, 0.5f * (dC.z + dC.w), ad);
    ad = fmaf(W11, 0.5f * (dC.w + dD), ad);
    float aw = Tp - T12;  // telescoped local weight sum

    // ===== weights -> A buffer (dep dead), b128 =====
    asm volatile("" ::: "memory");  // march reads precede wei writes
    *(float4*)&A[base + 0] = make_float4(W0, W1, W2, W3);
    *(float4*)&A[base + 4] = make_float4(W4, W5, W6, W7);
    *(float4*)&A[base + 8] = make_float4(W8, W9, W10, W11);

    // ===== quad reduction of depth/weight sums =====
#pragma unroll
    for (int off = 1; off <= 2; off <<= 1) {
        aw += __shfl_xor(aw, off);
        ad += __shfl_xor(ad, off);
    }
    // per-ray clamp == reference's global clamp on real outputs.
    float lastDep = __shfl(dC.w, lane | 3);    // ray's sample 47
    float firstDep = __shfl(dA.x, lane & ~3);  // ray's sample 0
    if (q == 0) {
        float d = ad / aw;
        d = fminf(fmaxf(d, firstDep), lastDep);
        out_depth[wray + r] = d;
    }

    // pin ALL color regs here: loads issued at kernel start cannot be sunk
    // below this point; their latency is covered by the march above.
    asm volatile("" : "+v"(u0.x), "+v"(u0.y), "+v"(u0.z), "+v"(u0.w),
                      "+v"(u1.x), "+v"(u1.y), "+v"(u1.z), "+v"(u1.w),
                      "+v"(u2.x), "+v"(u2.y), "+v"(u2.z), "+v"(u2.w),
                      "+v"(u3.x), "+v"(u3.y), "+v"(u3.z), "+v"(u3.w));
    asm volatile("" : "+v"(u4.x), "+v"(u4.y), "+v"(u4.z), "+v"(u4.w),
                      "+v"(u5.x), "+v"(u5.y), "+v"(u5.z), "+v"(u5.w),
                      "+v"(u6.x), "+v"(u6.y), "+v"(u6.z), "+v"(u6.w),
                      "+v"(u7.x), "+v"(u7.y), "+v"(u7.z), "+v"(u7.w),
                      "+v"(u8.x), "+v"(u8.y), "+v"(u8.z), "+v"(u8.w));

    // ===== v values (rgb needs v_s = 0.5*(W[s-1]+W[s])) — all in regs =====
    float Wm1 = __shfl_up(W11, 1);  // prev quad's last weight
    if (q == 0) Wm1 = 0.f;
    float v0 = 0.5f * (Wm1 + W0), v1 = 0.5f * (W0 + W1);
    float v2 = 0.5f * (W1 + W2), v3 = 0.5f * (W2 + W3);
    float v4 = 0.5f * (W3 + W4), v5 = 0.5f * (W4 + W5);
    float v6 = 0.5f * (W5 + W6), v7 = 0.5f * (W6 + W7);
    float v8 = 0.5f * (W7 + W8), v9 = 0.5f * (W8 + W9);
    float v10 = 0.5f * (W9 + W10), v11 = 0.5f * (W10 + W11);

    asm volatile("" ::: "memory");  // wei writes precede store-phase reads

    // ===== weight store: LDS(A) -> dense coalesced global =====
    {
        float* gw = out_w + wray * S_INTERVALS;
#pragma unroll
        for (int k = 0; k < 12; ++k) {
            int g = lane + k * 64;
            if (g < WR * S_INTERVALS) {  // 752
                int ray = g / S_INTERVALS;
                int s = g - ray * S_INTERVALS;
                gw[g] = A[ray * RSTRIDE + s];
            }
        }
    }

    // ===== color phase: 3 register-resident chunks through B =====
    float a0 = 0.f, a1 = 0.f, a2 = 0.f;

#define ACC4(vA, vB, vC, vD, fa, fb, fc)                                \
    do {                                                                \
        a0 = fmaf(vA, (fa).x, a0); a1 = fmaf(vA, (fa).y, a1);           \
        a2 = fmaf(vA, (fa).z, a2); a0 = fmaf(vB, (fa).w, a0);           \
        a1 = fmaf(vB, (fb).x, a1); a2 = fmaf(vB, (fb).y, a2);           \
        a0 = fmaf(vC, (fb).z, a0); a1 = fmaf(vC, (fb).w, a1);           \
        a2 = fmaf(vC, (fc).x, a2); a0 = fmaf(vD, (fc).y, a0);           \
        a1 = fmaf(vD, (fc).z, a1); a2 = fmaf(vD, (fc).w, a2);           \
    } while (0)
#define LD3(f, loc)                                                     \
    float4 f##a = *(const float4*)&B[rbase + (loc)];                    \
    float4 f##b = *(const float4*)&B[rbase + (loc) + 4];                \
    float4 f##c = *(const float4*)&B[rbase + (loc) + 8];
#define STAGE(pa, pb, pc)                                               \
    do {                                                                \
        *(float4*)&B[rr0 * RSTRIDE + i40 * 4] = pa;                     \
        *(float4*)&B[rr1 * RSTRIDE + i41 * 4] = pb;                     \
        *(float4*)&B[rr2 * RSTRIDE + i42 * 4] = pc;                     \
    } while (0)

    // ---- chunk 0 ----
    asm volatile("" ::: "memory");  // den reads done; tile overwrite ok
    STAGE(u0, u1, u2);
    asm volatile("" ::: "memory");
    if (q == 0) {
        LD3(x, 0) LD3(y, 12) LD3(z, 24)
        ACC4(v0, v1, v2, v3, xa, xb, xc);
        ACC4(v4, v5, v6, v7, ya, yb, yc);
        ACC4(v8, v9, v10, v11, za, zb, zc);
    } else if (q == 1) {
        LD3(x, 36)
        ACC4(v0, v1, v2, v3, xa, xb, xc);
    }
    // ---- chunk 1 ----
    asm volatile("" ::: "memory");
    STAGE(u3, u4, u5);
    asm volatile("" ::: "memory");
    if (q == 1) {
        LD3(x, 0) LD3(y, 12)
        ACC4(v4, v5, v6, v7, xa, xb, xc);
        ACC4(v8, v9, v10, v11, ya, yb, yc);
    } else if (q == 2) {
        LD3(x, 24) LD3(y, 36)
        ACC4(v0, v1, v2, v3, xa, xb, xc);
        ACC4(v4, v5, v6, v7, ya, yb, yc);
    }
    // ---- chunk 2 ----
    asm volatile("" ::: "memory");
    STAGE(u6, u7, u8);
    asm volatile("" ::: "memory");
    if (q == 2) {
        LD3(x, 0)
        ACC4(v8, v9, v10, v11, xa, xb, xc);
    } else if (q == 3) {
        LD3(x, 12) LD3(y, 24) LD3(z, 36)
        ACC4(v0, v1, v2, v3, xa, xb, xc);
        ACC4(v4, v5, v6, v7, ya, yb, yc);
        ACC4(v8, v9, v10, v11, za, zb, zc);
    }
#undef STAGE
#undef LD3
#undef ACC4

    // ===== quad reduction of rgb sums =====
#pragma unroll
    for (int off = 1; off <= 2; off <<= 1) {
        a0 += __shfl_xor(a0, off);
        a1 += __shfl_xor(a1, off);
        a2 += __shfl_xor(a2, off);
    }
    if (q == 0) {
        size_t rb = (wray + r) * 3;
        out_rgb[rb + 0] = fmaf(a0, 2.f, -1.f);
        out_rgb[rb + 1] = fmaf(a1, 2.f, -1.f);
        out_rgb[rb + 2] = fmaf(a2, 2.f, -1.f);
    }
}

extern "C" void kernel_launch(void* const* d_in, const int* in_sizes, int n_in,
                              void* d_out, int out_size, void* d_ws, size_t ws_size,
                              hipStream_t stream) {
    const float* colors = (const float*)d_in[0];
    const float* densities = (const float*)d_in[1];
    const float* depths = (const float*)d_in[2];

    const int nRays = in_sizes[2] / S_SAMPLES;  // 262144
    const int nWaves = nRays / WR;              // 16384
    const int nBlocks = nWaves / WAVES;         // 8192

    float* out = (float*)d_out;
    float* out_rgb = out;                        // nRays*3
    float* out_depth = out + (size_t)nRays * 3;  // nRays
    float* out_w = out + (size_t)nRays * 4;      // nRays*47

    raymarch_kernel<<<nBlocks, BT, 0, stream>>>(
        colors, densities, depths, out_rgb, out_depth, out_w, nRays);
}